// Round 4
// baseline (462.698 us; speedup 1.0000x reference)
//
#include <hip/hip_runtime.h>
#include <math.h>

typedef unsigned short u16;
typedef __bf16 bf16x8 __attribute__((ext_vector_type(8)));
typedef short s16x4 __attribute__((ext_vector_type(4)));
typedef short s16x8 __attribute__((ext_vector_type(8)));
typedef float f32x4 __attribute__((ext_vector_type(4)));

#define B_ 2
#define S_ 2048
#define D_ 2048
#define H_ 16
#define HD_ 128
#define M_ 4096
#define N3_ 6144

#define AS1(p) ((__attribute__((address_space(1))) void*)(void*)(p))
#define AS3(p) ((__attribute__((address_space(3))) void*)(p))
#define GLD16(g, l) __builtin_amdgcn_global_load_lds(AS1(g), AS3(l), 16, 0, 0)

__device__ __forceinline__ u16 f2bf(float f) {
  unsigned u = __float_as_uint(f);
  return (u16)((u + 0x7FFFu + ((u >> 16) & 1u)) >> 16);
}
__device__ __forceinline__ float bf2f(u16 v) {
  return __uint_as_float(((unsigned)v) << 16);
}

// ---------------- prep: all fp32->bf16 converts + RoPE table, one launch ----------------
__global__ void prep_k(const float* __restrict__ x, const float* __restrict__ wq,
                       const float* __restrict__ wk, const float* __restrict__ wv,
                       const float* __restrict__ wo, u16* __restrict__ xb,
                       u16* __restrict__ wqkvb, u16* __restrict__ wob,
                       float2* __restrict__ tab) {
  int idx = blockIdx.x * 256 + threadIdx.x;
  if (idx < 6291456) {
    const float* src;
    u16* dst;
    if (idx < 2097152) {
      src = x + (size_t)idx * 4;
      dst = xb + (size_t)idx * 4;
    } else if (idx < 5242880) {
      int ow = idx - 2097152;
      const float* w = ow < 1048576 ? wq : (ow < 2097152 ? wk : wv);
      int wo_off = ow & 1048575;
      src = w + (size_t)wo_off * 4;
      dst = wqkvb + (size_t)ow * 4;
    } else {
      int ow = idx - 5242880;
      src = wo + (size_t)ow * 4;
      dst = wob + (size_t)ow * 4;
    }
    float4 v = *(const float4*)src;
    ushort4 o;
    o.x = f2bf(v.x); o.y = f2bf(v.y); o.z = f2bf(v.z); o.w = f2bf(v.w);
    *(ushort4*)dst = o;
  } else {
    int t = idx - 6291456; // [0, S_*64)
    int s = t >> 6, i = t & 63;
    double inv = exp2(-(double)i * (13.287712379549449 / 64.0)); // 10000^(-i/64)
    double fr = (double)s * inv;
    double sv, cv;
    sincos(fr, &sv, &cv);
    tab[t] = make_float2((float)cv, (float)sv);
  }
}

// ---------------- GEMM: C[m][n] = sum_k A[m][k] * B[n][k], bf16 in, fp32 acc ----------------
template <typename OT>
__global__ __launch_bounds__(256) void gemm_bt_k(const u16* __restrict__ A,
                                                 const u16* __restrict__ B,
                                                 OT* __restrict__ C,
                                                 int M, int N, int K) {
  __shared__ alignas(16) u16 As[128 * 32];
  __shared__ alignas(16) u16 Bs[128 * 32];
  const int tid = threadIdx.x;
  const int wave = tid >> 6, lane = tid & 63;
  const int quad = lane >> 4, l16 = lane & 15;
  const int m0 = blockIdx.y * 128, n0 = blockIdx.x * 128;
  const int wm = (wave >> 1) * 64, wn = (wave & 1) * 64;
  const u16* Ag = A + (size_t)m0 * K;
  const u16* Bg = B + (size_t)n0 * K;
  f32x4 acc[4][4] = {};
  const int c0 = tid, c1 = tid + 256;
  const int r0 = c0 >> 2, k0b = (c0 & 3) * 8;
  const int r1 = c1 >> 2, k1b = (c1 & 3) * 8;
  u16* la0 = As + (size_t)(wave * 64) * 8;
  u16* la1 = As + (size_t)(256 + wave * 64) * 8;
  u16* lb0 = Bs + (size_t)(wave * 64) * 8;
  u16* lb1 = Bs + (size_t)(256 + wave * 64) * 8;
  for (int kt = 0; kt < K; kt += 32) {
    GLD16(Ag + (size_t)r0 * K + kt + k0b, la0);
    GLD16(Ag + (size_t)r1 * K + kt + k1b, la1);
    GLD16(Bg + (size_t)r0 * K + kt + k0b, lb0);
    GLD16(Bg + (size_t)r1 * K + kt + k1b, lb1);
    __syncthreads();
    bf16x8 af[4], bfr[4];
#pragma unroll
    for (int i = 0; i < 4; ++i)
      af[i] = *(const bf16x8*)&As[(wm + i * 16 + l16) * 32 + quad * 8];
#pragma unroll
    for (int j = 0; j < 4; ++j)
      bfr[j] = *(const bf16x8*)&Bs[(wn + j * 16 + l16) * 32 + quad * 8];
#pragma unroll
    for (int i = 0; i < 4; ++i)
#pragma unroll
      for (int j = 0; j < 4; ++j)
        acc[i][j] = __builtin_amdgcn_mfma_f32_16x16x32_bf16(af[i], bfr[j], acc[i][j], 0, 0, 0);
    __syncthreads();
  }
#pragma unroll
  for (int i = 0; i < 4; ++i) {
#pragma unroll
    for (int j = 0; j < 4; ++j) {
      int n = n0 + wn + j * 16 + l16;
#pragma unroll
      for (int r = 0; r < 4; ++r) {
        int m = m0 + wm + i * 16 + quad * 4 + r;
        if constexpr (sizeof(OT) == 4)
          C[(size_t)m * N + n] = acc[i][j][r];
        else
          C[(size_t)m * N + n] = f2bf(acc[i][j][r]);
      }
    }
  }
}

// ---------------- RoPE apply (q,k) + V permute, one launch ----------------
__global__ void rv_k(const u16* __restrict__ qkv, const float2* __restrict__ tab,
                     u16* __restrict__ Qr, u16* __restrict__ Kr, u16* __restrict__ Vp) {
  int idx = blockIdx.x * 256 + threadIdx.x;
  if (idx < 4194304) {
    int m = idx >> 10;
    int h = (idx >> 6) & 15;
    int i = idx & 63;
    int s = m & (S_ - 1);
    int b = m >> 11;
    float2 cs = tab[(s << 6) | i];
    const u16* qp = qkv + (size_t)m * N3_ + h * HD_ + 2 * i;
    ushort2 qv = *(const ushort2*)qp;
    ushort2 kv = *(const ushort2*)(qp + D_);
    float qr = bf2f(qv.x), qi = bf2f(qv.y);
    float kr = bf2f(kv.x), ki = bf2f(kv.y);
    ushort2 qo, ko;
    qo.x = f2bf(qr * cs.x - qi * cs.y);
    qo.y = f2bf(qr * cs.y + qi * cs.x);
    ko.x = f2bf(kr * cs.x - ki * cs.y);
    ko.y = f2bf(kr * cs.y + ki * cs.x);
    size_t o = ((size_t)(b * H_ + h) * S_ + s) * HD_ + 2 * i;
    *(ushort2*)(Qr + o) = qo;
    *(ushort2*)(Kr + o) = ko;
  } else {
    int u = idx - 4194304;
    int bh = u >> 16, t = u & 65535;
    int b = bh >> 4, h = bh & 15;
    int d = t & 127, g = t >> 7;
    const u16* src = qkv + ((size_t)(b * S_ + 4 * g)) * N3_ + 2 * D_ + h * HD_ + d;
    ushort4 o;
    o.x = src[0];
    o.y = src[N3_];
    o.z = src[2 * N3_];
    o.w = src[3 * N3_];
    *(ushort4*)(Vp + (size_t)bh * S_ * HD_ + (size_t)t * 4) = o;
  }
}

// ---------------- Flash attention, S^T formulation, kv-split x2 ----------------
#if __has_builtin(__builtin_amdgcn_mfma_f32_16x16x16bf16_1k)
#define HAS_MFMA16 1
#endif

__global__ __launch_bounds__(256, 3) void flash_k(const u16* __restrict__ Q,
                                                  const u16* __restrict__ Kc,
                                                  const u16* __restrict__ Vp,
                                                  float* __restrict__ Op0,
                                                  float* __restrict__ Op1,
                                                  float* __restrict__ lbuf) {
  __shared__ alignas(16) u16 sm[16384];
  u16* Ks = sm;         // 64 x 128 (swizzled)
  u16* Vs = sm + 8192;  // [16 g][128 d][4]
  const int tid = threadIdx.x;
  const int wave = tid >> 6, lane = tid & 63;
  const int quad = lane >> 4, l16 = lane & 15;
  const int qt = blockIdx.x;
  const int bh = blockIdx.y & 31, split = blockIdx.y >> 5;
  const int b = bh >> 4, h = bh & 15;

  // stage Q (row-XOR swizzled 16B chunks) into the full 16K region twice?
  // No: Q is 32KB; stage as two 16KB halves, consuming fragments between.
  // Simpler: stage half (rows 0..63), read frags for waves 0/1 region... but
  // all waves need their own 32 rows; rows = wave*32.. so rows 0..127 needed.
  // Stage Q in two passes over the same 16KB LDS: rows 0..63 then 64..127.
  bf16x8 qf[2][4];
#pragma unroll
  for (int half = 0; half < 2; ++half) {
#pragma unroll
    for (int i = 0; i < 4; ++i) {
      int c = i * 256 + tid, row = c >> 4, jl = c & 15;
      int gj = (jl & 8) | ((jl ^ row) & 7);
      GLD16(Q + ((size_t)bh * S_ + qt * 128 + half * 64 + row) * HD_ + gj * 8,
            sm + (size_t)(i * 256 + wave * 64) * 8);
    }
    __syncthreads();
    // waves owning rows in this half load their fragments
    if ((wave >> 1) == half) {
      int wrow = (wave & 1) * 32; // row base within this 64-row half
#pragma unroll
      for (int qs = 0; qs < 2; ++qs) {
        int row = wrow + qs * 16 + l16;
#pragma unroll
        for (int dk = 0; dk < 4; ++dk) {
          int c = dk * 4 + quad, pj = (c & 8) | ((c ^ row) & 7);
          qf[qs][dk] = *(const bf16x8*)&sm[row * 128 + pj * 8];
        }
      }
    }
    __syncthreads();
  }

  f32x4 acco[2][8] = {};
  f32x4 accl[2] = {};
  const float SCL = 0.08838834764831845f * 1.4426950408889634f; // 1/sqrt(128)*log2(e)
#ifdef HAS_MFMA16
  const s16x4 ones = {(short)0x3F80, (short)0x3F80, (short)0x3F80, (short)0x3F80};
#else
  union { s16x8 s; bf16x8 b; } onesu;
  onesu.s = (s16x8){(short)0x3F80, (short)0x3F80, (short)0x3F80, (short)0x3F80,
                    (short)0x3F80, (short)0x3F80, (short)0x3F80, (short)0x3F80};
#endif

  const int kt0 = split * 16, kt1 = kt0 + 16;
#pragma unroll 1
  for (int kt = kt0; kt < kt1; ++kt) {
    // stage K tile (64 x 128), swizzled
#pragma unroll
    for (int i = 0; i < 4; ++i) {
      int c = i * 256 + tid, row = c >> 4, jl = c & 15;
      int gj = (jl & 8) | ((jl ^ row) & 7);
      GLD16(Kc + ((size_t)bh * S_ + kt * 64 + row) * HD_ + gj * 8,
            Ks + (size_t)(i * 256 + wave * 64) * 8);
    }
    // stage Vp tile (16 KB contiguous, natural layout)
    const u16* vg = Vp + (size_t)bh * S_ * HD_ + (size_t)kt * 8192;
#pragma unroll
    for (int i = 0; i < 4; ++i)
      GLD16(vg + (size_t)(i * 256 + tid) * 8, Vs + (size_t)(i * 256 + wave * 64) * 8);
    __syncthreads();

    // S^T = K Q^T : A = K rows (m=kv), B = Q (n=q)
    f32x4 sc[2][4] = {};
#pragma unroll
    for (int k4 = 0; k4 < 4; ++k4) {
      int row = k4 * 16 + l16;
#pragma unroll
      for (int dk = 0; dk < 4; ++dk) {
        int c = dk * 4 + quad, pj = (c & 8) | ((c ^ row) & 7);
        bf16x8 kf = *(const bf16x8*)&Ks[row * 128 + pj * 8];
        sc[0][k4] = __builtin_amdgcn_mfma_f32_16x16x32_bf16(kf, qf[0][dk], sc[0][k4], 0, 0, 0);
        sc[1][k4] = __builtin_amdgcn_mfma_f32_16x16x32_bf16(kf, qf[1][dk], sc[1][k4], 0, 0, 0);
      }
    }

    // P = exp2(S^T * scl), packed to bf16 A-frags (k = kv = quad*4+j)
#ifdef HAS_MFMA16
    s16x4 ap[2][4];
#else
    bf16x8 ap[2][4];
#endif
#pragma unroll
    for (int qs = 0; qs < 2; ++qs) {
#pragma unroll
      for (int k4 = 0; k4 < 4; ++k4) {
        f32x4 s = sc[qs][k4];
        u16 p0 = f2bf(__builtin_amdgcn_exp2f(s[0] * SCL));
        u16 p1 = f2bf(__builtin_amdgcn_exp2f(s[1] * SCL));
        u16 p2 = f2bf(__builtin_amdgcn_exp2f(s[2] * SCL));
        u16 p3 = f2bf(__builtin_amdgcn_exp2f(s[3] * SCL));
#ifdef HAS_MFMA16
        ap[qs][k4] = (s16x4){(short)p0, (short)p1, (short)p2, (short)p3};
#else
        union { s16x8 s8; bf16x8 b8; } u;
        u.s8 = (s16x8){(short)p0, (short)p1, (short)p2, (short)p3, 0, 0, 0, 0};
        ap[qs][k4] = u.b8;
#endif
      }
    }

    // O += P V (P from regs; V b-frag = one b64 read), l via ones-MFMA
#pragma unroll
    for (int ck = 0; ck < 4; ++ck) {
      int vbase = (ck * 4 + quad) * 512 + l16 * 4;
#pragma unroll
      for (int df = 0; df < 8; ++df) {
        s16x4 bv = *(const s16x4*)&Vs[vbase + df * 64];
#ifdef HAS_MFMA16
        acco[0][df] = __builtin_amdgcn_mfma_f32_16x16x16bf16_1k(ap[0][ck], bv, acco[0][df], 0, 0, 0);
        acco[1][df] = __builtin_amdgcn_mfma_f32_16x16x16bf16_1k(ap[1][ck], bv, acco[1][df], 0, 0, 0);
#else
        union { s16x8 s8; bf16x8 b8; } vb;
        vb.s8 = (s16x8){bv[0], bv[1], bv[2], bv[3], 0, 0, 0, 0};
        acco[0][df] = __builtin_amdgcn_mfma_f32_16x16x32_bf16(ap[0][ck], vb.b8, acco[0][df], 0, 0, 0);
        acco[1][df] = __builtin_amdgcn_mfma_f32_16x16x32_bf16(ap[1][ck], vb.b8, acco[1][df], 0, 0, 0);
#endif
      }
#ifdef HAS_MFMA16
      accl[0] = __builtin_amdgcn_mfma_f32_16x16x16bf16_1k(ones, ap[0][ck], accl[0], 0, 0, 0);
      accl[1] = __builtin_amdgcn_mfma_f32_16x16x16bf16_1k(ones, ap[1][ck], accl[1], 0, 0, 0);
#else
      accl[0] = __builtin_amdgcn_mfma_f32_16x16x32_bf16(onesu.b, ap[0][ck], accl[0], 0, 0, 0);
      accl[1] = __builtin_amdgcn_mfma_f32_16x16x32_bf16(onesu.b, ap[1][ck], accl[1], 0, 0, 0);
#endif
    }
    __syncthreads();
  }

  // epilogue: unnormalized O-partial (fp32) + row sums l
  float* op = split ? Op1 : Op0;
#pragma unroll
  for (int qs = 0; qs < 2; ++qs) {
    int rowb = qt * 128 + wave * 32 + qs * 16 + quad * 4;
#pragma unroll
    for (int df = 0; df < 8; ++df) {
      int col = h * HD_ + df * 16 + l16;
#pragma unroll
      for (int r = 0; r < 4; ++r)
        op[((size_t)(b * S_ + rowb + r)) * D_ + col] = acco[qs][df][r];
    }
    if (quad == 0)
      lbuf[(size_t)split * 65536 + bh * 2048 + qt * 128 + wave * 32 + qs * 16 + l16] =
          accl[qs][0];
  }
}

// ---------------- merge kv-split partials -> bf16 Ob ----------------
__global__ void merge_k(const float* __restrict__ Op0, const float* __restrict__ Op1,
                        const float* __restrict__ lbuf, u16* __restrict__ Ob) {
  int i4 = blockIdx.x * 256 + threadIdx.x; // over M_*D_/4
  int row = i4 >> 9, col4 = i4 & 511;
  int b = row >> 11, s = row & 2047, h4 = col4 >> 5;
  int bh = (b << 4) | h4;
  float l = lbuf[bh * 2048 + s] + lbuf[65536 + bh * 2048 + s];
  float inv = 1.0f / l;
  float4 a = ((const float4*)Op0)[i4];
  float4 c = ((const float4*)Op1)[i4];
  ushort4 o;
  o.x = f2bf((a.x + c.x) * inv);
  o.y = f2bf((a.y + c.y) * inv);
  o.z = f2bf((a.z + c.z) * inv);
  o.w = f2bf((a.w + c.w) * inv);
  ((ushort4*)Ob)[i4] = o;
}

extern "C" void kernel_launch(void* const* d_in, const int* in_sizes, int n_in,
                              void* d_out, int out_size, void* d_ws, size_t ws_size,
                              hipStream_t stream) {
  const float* x  = (const float*)d_in[0];
  const float* wq = (const float*)d_in[1];
  const float* wk = (const float*)d_in[2];
  const float* wv = (const float*)d_in[3];
  const float* wo = (const float*)d_in[4];

  size_t off = 0;
  char* ws = (char*)d_ws;
  u16* xb    = (u16*)(ws + off); off += (size_t)M_ * D_ * 2;          // 0..16 MiB
  u16* wqkvb = (u16*)(ws + off); off += (size_t)3 * D_ * D_ * 2;      // 16..40 MiB
  u16* wob   = (u16*)(ws + off); off += (size_t)D_ * D_ * 2;          // 40..48 MiB
  u16* qkv   = (u16*)(ws + off); off += (size_t)M_ * N3_ * 2;         // 48..96 MiB
  u16* Qr    = (u16*)(ws + off); off += (size_t)M_ * D_ * 2;          // 96..112 MiB
  u16* Kr    = (u16*)(ws + off); off += (size_t)M_ * D_ * 2;          // 112..128 MiB
  u16* Vp    = (u16*)(ws + off); off += (size_t)M_ * D_ * 2;          // 128..144 MiB
  float2* tab = (float2*)(ws + off); off += (size_t)S_ * 64 * sizeof(float2); // 144..145 MiB
  // Overlays (verified disjoint by byte ranges):
  //   Op0 (32 MiB): 0..32 MiB      inside xb+wqkvb (dead after QKV GEMM); wob untouched
  //   Ob  (16 MiB): 48..64 MiB     = qkv base (dead after rv_k)
  //   Op1 (32 MiB): 64..96 MiB     = qkv upper (dead after rv_k); disjoint from Ob
  //   lbuf (512 KB): tab region (dead after rv_k)
  float* Op0  = (float*)ws;
  u16*   Ob   = qkv;
  float* Op1  = (float*)(ws + ((size_t)64 << 20));
  float* lbuf = (float*)tab;
  if (off > ws_size) return;

  prep_k<<<25088, 256, 0, stream>>>(x, wq, wk, wv, wo, xb, wqkvb, wob, tab);
  gemm_bt_k<u16><<<dim3(N3_ / 128, M_ / 128), 256, 0, stream>>>(xb, wqkvb, qkv, M_, N3_, D_);
  rv_k<<<24576, 256, 0, stream>>>(qkv, tab, Qr, Kr, Vp);
  flash_k<<<dim3(S_ / 128, 64), 256, 0, stream>>>(Qr, Kr, Vp, Op0, Op1, lbuf);
  merge_k<<<(M_ * D_ / 4) / 256, 256, 0, stream>>>(Op0, Op1, lbuf, Ob);
  gemm_bt_k<float><<<dim3(D_ / 128, M_ / 128), 256, 0, stream>>>(Ob, wob, (float*)d_out, M_, D_, D_);
}

// Round 5
// 444.525 us; speedup vs baseline: 1.0409x; 1.0409x over previous
//
#include <hip/hip_runtime.h>
#include <math.h>

typedef unsigned short u16;
typedef __bf16 bf16x8 __attribute__((ext_vector_type(8)));
typedef short s16x4 __attribute__((ext_vector_type(4)));
typedef short s16x8 __attribute__((ext_vector_type(8)));
typedef float f32x4 __attribute__((ext_vector_type(4)));

#define B_ 2
#define S_ 2048
#define D_ 2048
#define H_ 16
#define HD_ 128
#define M_ 4096
#define N3_ 6144

#define AS1(p) ((__attribute__((address_space(1))) void*)(void*)(p))
#define AS3(p) ((__attribute__((address_space(3))) void*)(p))
#define GLD16(g, l) __builtin_amdgcn_global_load_lds(AS1(g), AS3(l), 16, 0, 0)

__device__ __forceinline__ u16 f2bf(float f) {
  unsigned u = __float_as_uint(f);
  return (u16)((u + 0x7FFFu + ((u >> 16) & 1u)) >> 16);
}
__device__ __forceinline__ float bf2f(u16 v) {
  return __uint_as_float(((unsigned)v) << 16);
}

// ---------------- prep: all fp32->bf16 converts + RoPE table, one launch ----------------
__global__ void prep_k(const float* __restrict__ x, const float* __restrict__ wq,
                       const float* __restrict__ wk, const float* __restrict__ wv,
                       const float* __restrict__ wo, u16* __restrict__ xb,
                       u16* __restrict__ wqkvb, u16* __restrict__ wob,
                       float2* __restrict__ tab) {
  int idx = blockIdx.x * 256 + threadIdx.x;
  if (idx < 6291456) {
    const float* src;
    u16* dst;
    if (idx < 2097152) {
      src = x + (size_t)idx * 4;
      dst = xb + (size_t)idx * 4;
    } else if (idx < 5242880) {
      int ow = idx - 2097152;
      const float* w = ow < 1048576 ? wq : (ow < 2097152 ? wk : wv);
      int wo_off = ow & 1048575;
      src = w + (size_t)wo_off * 4;
      dst = wqkvb + (size_t)ow * 4;
    } else {
      int ow = idx - 5242880;
      src = wo + (size_t)ow * 4;
      dst = wob + (size_t)ow * 4;
    }
    float4 v = *(const float4*)src;
    ushort4 o;
    o.x = f2bf(v.x); o.y = f2bf(v.y); o.z = f2bf(v.z); o.w = f2bf(v.w);
    *(ushort4*)dst = o;
  } else {
    int t = idx - 6291456; // [0, S_*64)
    int s = t >> 6, i = t & 63;
    double inv = exp2(-(double)i * (13.287712379549449 / 64.0)); // 10000^(-i/64)
    double fr = (double)s * inv;
    double sv, cv;
    sincos(fr, &sv, &cv);
    tab[t] = make_float2((float)cv, (float)sv);
  }
}

// ---------------- QKV GEMM with fused RoPE + relayout epilogue ----------------
// C[m][n] = sum_k x[m][k] * Wqkv[n][k]; n-tile (128) = exactly one head of one
// region (q/k/v). Epilogue: q/k -> RoPE (partner via shfl_xor(1)) -> Qr/Kr
// [bh][s][d]; v -> Vp [bh][s/4][d][4] (C-layout rows quad*4+r are 4 consecutive
// s -> one ushort4 store per fragment).
__global__ __launch_bounds__(256) void gemm_qkv_k(const u16* __restrict__ A,
                                                  const u16* __restrict__ B,
                                                  const float2* __restrict__ tab,
                                                  u16* __restrict__ Qr,
                                                  u16* __restrict__ Kr,
                                                  u16* __restrict__ Vp) {
  __shared__ alignas(16) u16 As[128 * 32];
  __shared__ alignas(16) u16 Bs[128 * 32];
  const int K = D_;
  const int tid = threadIdx.x;
  const int wave = tid >> 6, lane = tid & 63;
  const int quad = lane >> 4, l16 = lane & 15;
  const int m0 = blockIdx.y * 128, n0 = blockIdx.x * 128;
  const int wm = (wave >> 1) * 64, wn = (wave & 1) * 64;
  const u16* Ag = A + (size_t)m0 * K;
  const u16* Bg = B + (size_t)n0 * K;
  f32x4 acc[4][4] = {};
  const int c0 = tid, c1 = tid + 256;
  const int r0 = c0 >> 2, k0b = (c0 & 3) * 8;
  const int r1 = c1 >> 2, k1b = (c1 & 3) * 8;
  u16* la0 = As + (size_t)(wave * 64) * 8;
  u16* la1 = As + (size_t)(256 + wave * 64) * 8;
  u16* lb0 = Bs + (size_t)(wave * 64) * 8;
  u16* lb1 = Bs + (size_t)(256 + wave * 64) * 8;
  for (int kt = 0; kt < K; kt += 32) {
    GLD16(Ag + (size_t)r0 * K + kt + k0b, la0);
    GLD16(Ag + (size_t)r1 * K + kt + k1b, la1);
    GLD16(Bg + (size_t)r0 * K + kt + k0b, lb0);
    GLD16(Bg + (size_t)r1 * K + kt + k1b, lb1);
    __syncthreads();
    bf16x8 af[4], bfr[4];
#pragma unroll
    for (int i = 0; i < 4; ++i)
      af[i] = *(const bf16x8*)&As[(wm + i * 16 + l16) * 32 + quad * 8];
#pragma unroll
    for (int j = 0; j < 4; ++j)
      bfr[j] = *(const bf16x8*)&Bs[(wn + j * 16 + l16) * 32 + quad * 8];
#pragma unroll
    for (int i = 0; i < 4; ++i)
#pragma unroll
      for (int j = 0; j < 4; ++j)
        acc[i][j] = __builtin_amdgcn_mfma_f32_16x16x32_bf16(af[i], bfr[j], acc[i][j], 0, 0, 0);
    __syncthreads();
  }

  const int region = n0 >> 11;       // 0=q, 1=k, 2=v
  const int h = (n0 >> 7) & 15;
  if (region < 2) {
    u16* dst = region ? Kr : Qr;
#pragma unroll
    for (int i = 0; i < 4; ++i) {
#pragma unroll
      for (int j = 0; j < 4; ++j) {
        int d = wn + j * 16 + l16;    // 0..127 within head
        int ii = d >> 1;
        float sgn = (d & 1) ? 1.f : -1.f;
#pragma unroll
        for (int r = 0; r < 4; ++r) {
          int m = m0 + wm + i * 16 + quad * 4 + r;
          int s = m & (S_ - 1), b = m >> 11;
          float2 cs = tab[(s << 6) + ii];
          float v = acc[i][j][r];
          float p = __shfl_xor(v, 1);
          float o = v * cs.x + sgn * p * cs.y;
          dst[((size_t)((b << 4) + h) * S_ + s) * HD_ + d] = f2bf(o);
        }
      }
    }
  } else {
#pragma unroll
    for (int i = 0; i < 4; ++i) {
#pragma unroll
      for (int j = 0; j < 4; ++j) {
        int d = wn + j * 16 + l16;
        int rowb = m0 + wm + i * 16 + quad * 4; // multiple of 4
        int b = rowb >> 11, sl = rowb & (S_ - 1);
        ushort4 o;
        o.x = f2bf(acc[i][j][0]);
        o.y = f2bf(acc[i][j][1]);
        o.z = f2bf(acc[i][j][2]);
        o.w = f2bf(acc[i][j][3]);
        *(ushort4*)(Vp + (size_t)((b << 4) + h) * S_ * HD_ + (size_t)(sl >> 2) * 512 + d * 4) = o;
      }
    }
  }
}

// ---------------- generic GEMM (output projection) ----------------
template <typename OT>
__global__ __launch_bounds__(256) void gemm_bt_k(const u16* __restrict__ A,
                                                 const u16* __restrict__ B,
                                                 OT* __restrict__ C,
                                                 int M, int N, int K) {
  __shared__ alignas(16) u16 As[128 * 32];
  __shared__ alignas(16) u16 Bs[128 * 32];
  const int tid = threadIdx.x;
  const int wave = tid >> 6, lane = tid & 63;
  const int quad = lane >> 4, l16 = lane & 15;
  const int m0 = blockIdx.y * 128, n0 = blockIdx.x * 128;
  const int wm = (wave >> 1) * 64, wn = (wave & 1) * 64;
  const u16* Ag = A + (size_t)m0 * K;
  const u16* Bg = B + (size_t)n0 * K;
  f32x4 acc[4][4] = {};
  const int c0 = tid, c1 = tid + 256;
  const int r0 = c0 >> 2, k0b = (c0 & 3) * 8;
  const int r1 = c1 >> 2, k1b = (c1 & 3) * 8;
  u16* la0 = As + (size_t)(wave * 64) * 8;
  u16* la1 = As + (size_t)(256 + wave * 64) * 8;
  u16* lb0 = Bs + (size_t)(wave * 64) * 8;
  u16* lb1 = Bs + (size_t)(256 + wave * 64) * 8;
  for (int kt = 0; kt < K; kt += 32) {
    GLD16(Ag + (size_t)r0 * K + kt + k0b, la0);
    GLD16(Ag + (size_t)r1 * K + kt + k1b, la1);
    GLD16(Bg + (size_t)r0 * K + kt + k0b, lb0);
    GLD16(Bg + (size_t)r1 * K + kt + k1b, lb1);
    __syncthreads();
    bf16x8 af[4], bfr[4];
#pragma unroll
    for (int i = 0; i < 4; ++i)
      af[i] = *(const bf16x8*)&As[(wm + i * 16 + l16) * 32 + quad * 8];
#pragma unroll
    for (int j = 0; j < 4; ++j)
      bfr[j] = *(const bf16x8*)&Bs[(wn + j * 16 + l16) * 32 + quad * 8];
#pragma unroll
    for (int i = 0; i < 4; ++i)
#pragma unroll
      for (int j = 0; j < 4; ++j)
        acc[i][j] = __builtin_amdgcn_mfma_f32_16x16x32_bf16(af[i], bfr[j], acc[i][j], 0, 0, 0);
    __syncthreads();
  }
#pragma unroll
  for (int i = 0; i < 4; ++i) {
#pragma unroll
    for (int j = 0; j < 4; ++j) {
      int n = n0 + wn + j * 16 + l16;
#pragma unroll
      for (int r = 0; r < 4; ++r) {
        int m = m0 + wm + i * 16 + quad * 4 + r;
        if constexpr (sizeof(OT) == 4)
          C[(size_t)m * N + n] = acc[i][j][r];
        else
          C[(size_t)m * N + n] = f2bf(acc[i][j][r]);
      }
    }
  }
}

// ---------------- Flash attention, S^T formulation, no split ----------------
#if __has_builtin(__builtin_amdgcn_mfma_f32_16x16x16bf16_1k)
#define HAS_MFMA16 1
#endif

__global__ __launch_bounds__(256, 3) void flash_k(const u16* __restrict__ Q,
                                                  const u16* __restrict__ Kc,
                                                  const u16* __restrict__ Vp,
                                                  u16* __restrict__ O) {
  __shared__ alignas(16) u16 sm[16384];
  u16* Ks = sm;         // 64 x 128 (swizzled)
  u16* Vs = sm + 8192;  // [16 g][128 d][4]
  const int tid = threadIdx.x;
  const int wave = tid >> 6, lane = tid & 63;
  const int quad = lane >> 4, l16 = lane & 15;
  const int qt = blockIdx.x, bh = blockIdx.y;
  const int b = bh >> 4, h = bh & 15;

  // Q (32KB) staged in two 16KB passes over the same LDS region
  bf16x8 qf[2][4];
#pragma unroll
  for (int half = 0; half < 2; ++half) {
#pragma unroll
    for (int i = 0; i < 4; ++i) {
      int c = i * 256 + tid, row = c >> 4, jl = c & 15;
      int gj = (jl & 8) | ((jl ^ row) & 7);
      GLD16(Q + ((size_t)bh * S_ + qt * 128 + half * 64 + row) * HD_ + gj * 8,
            sm + (size_t)(i * 256 + wave * 64) * 8);
    }
    __syncthreads();
    if ((wave >> 1) == half) {
      int wrow = (wave & 1) * 32;
#pragma unroll
      for (int qs = 0; qs < 2; ++qs) {
        int row = wrow + qs * 16 + l16;
#pragma unroll
        for (int dk = 0; dk < 4; ++dk) {
          int c = dk * 4 + quad, pj = (c & 8) | ((c ^ row) & 7);
          qf[qs][dk] = *(const bf16x8*)&sm[row * 128 + pj * 8];
        }
      }
    }
    __syncthreads();
  }

  f32x4 acco[2][8] = {};
  f32x4 accl[2] = {};
  const float SCL = 0.08838834764831845f * 1.4426950408889634f; // 1/sqrt(128)*log2(e)
#ifdef HAS_MFMA16
  const s16x4 ones = {(short)0x3F80, (short)0x3F80, (short)0x3F80, (short)0x3F80};
#else
  union { s16x8 s; bf16x8 b; } onesu;
  onesu.s = (s16x8){(short)0x3F80, (short)0x3F80, (short)0x3F80, (short)0x3F80,
                    (short)0x3F80, (short)0x3F80, (short)0x3F80, (short)0x3F80};
#endif

#pragma unroll 1
  for (int kt = 0; kt < 32; ++kt) {
    // stage K tile (64 x 128), swizzled
#pragma unroll
    for (int i = 0; i < 4; ++i) {
      int c = i * 256 + tid, row = c >> 4, jl = c & 15;
      int gj = (jl & 8) | ((jl ^ row) & 7);
      GLD16(Kc + ((size_t)bh * S_ + kt * 64 + row) * HD_ + gj * 8,
            Ks + (size_t)(i * 256 + wave * 64) * 8);
    }
    // stage Vp tile (16 KB contiguous, natural layout)
    const u16* vg = Vp + (size_t)bh * S_ * HD_ + (size_t)kt * 8192;
#pragma unroll
    for (int i = 0; i < 4; ++i)
      GLD16(vg + (size_t)(i * 256 + tid) * 8, Vs + (size_t)(i * 256 + wave * 64) * 8);
    __syncthreads();

    // S^T = K Q^T
    f32x4 sc[2][4] = {};
#pragma unroll
    for (int k4 = 0; k4 < 4; ++k4) {
      int row = k4 * 16 + l16;
#pragma unroll
      for (int dk = 0; dk < 4; ++dk) {
        int c = dk * 4 + quad, pj = (c & 8) | ((c ^ row) & 7);
        bf16x8 kf = *(const bf16x8*)&Ks[row * 128 + pj * 8];
        sc[0][k4] = __builtin_amdgcn_mfma_f32_16x16x32_bf16(kf, qf[0][dk], sc[0][k4], 0, 0, 0);
        sc[1][k4] = __builtin_amdgcn_mfma_f32_16x16x32_bf16(kf, qf[1][dk], sc[1][k4], 0, 0, 0);
      }
    }

    // P = exp2(S^T * scl), packed to bf16 A-frags (k = kv = quad*4+j)
#ifdef HAS_MFMA16
    s16x4 ap[2][4];
#else
    bf16x8 ap[2][4];
#endif
#pragma unroll
    for (int qs = 0; qs < 2; ++qs) {
#pragma unroll
      for (int k4 = 0; k4 < 4; ++k4) {
        f32x4 s = sc[qs][k4];
        u16 p0 = f2bf(__builtin_amdgcn_exp2f(s[0] * SCL));
        u16 p1 = f2bf(__builtin_amdgcn_exp2f(s[1] * SCL));
        u16 p2 = f2bf(__builtin_amdgcn_exp2f(s[2] * SCL));
        u16 p3 = f2bf(__builtin_amdgcn_exp2f(s[3] * SCL));
#ifdef HAS_MFMA16
        ap[qs][k4] = (s16x4){(short)p0, (short)p1, (short)p2, (short)p3};
#else
        union { s16x8 s8; bf16x8 b8; } u;
        u.s8 = (s16x8){(short)p0, (short)p1, (short)p2, (short)p3, 0, 0, 0, 0};
        ap[qs][k4] = u.b8;
#endif
      }
    }

    // O += P V; l via ones-MFMA
#pragma unroll
    for (int ck = 0; ck < 4; ++ck) {
      int vbase = (ck * 4 + quad) * 512 + l16 * 4;
#pragma unroll
      for (int df = 0; df < 8; ++df) {
        s16x4 bv = *(const s16x4*)&Vs[vbase + df * 64];
#ifdef HAS_MFMA16
        acco[0][df] = __builtin_amdgcn_mfma_f32_16x16x16bf16_1k(ap[0][ck], bv, acco[0][df], 0, 0, 0);
        acco[1][df] = __builtin_amdgcn_mfma_f32_16x16x16bf16_1k(ap[1][ck], bv, acco[1][df], 0, 0, 0);
#else
        union { s16x8 s8; bf16x8 b8; } vb;
        vb.s8 = (s16x8){bv[0], bv[1], bv[2], bv[3], 0, 0, 0, 0};
        acco[0][df] = __builtin_amdgcn_mfma_f32_16x16x32_bf16(ap[0][ck], vb.b8, acco[0][df], 0, 0, 0);
        acco[1][df] = __builtin_amdgcn_mfma_f32_16x16x32_bf16(ap[1][ck], vb.b8, acco[1][df], 0, 0, 0);
#endif
      }
#ifdef HAS_MFMA16
      accl[0] = __builtin_amdgcn_mfma_f32_16x16x16bf16_1k(ones, ap[0][ck], accl[0], 0, 0, 0);
      accl[1] = __builtin_amdgcn_mfma_f32_16x16x16bf16_1k(ones, ap[1][ck], accl[1], 0, 0, 0);
#else
      accl[0] = __builtin_amdgcn_mfma_f32_16x16x32_bf16(onesu.b, ap[0][ck], accl[0], 0, 0, 0);
      accl[1] = __builtin_amdgcn_mfma_f32_16x16x32_bf16(onesu.b, ap[1][ck], accl[1], 0, 0, 0);
#endif
    }
    __syncthreads();
  }

  // epilogue: normalized bf16 O[b][s][h*128+d]
#pragma unroll
  for (int qs = 0; qs < 2; ++qs) {
    float lv = accl[qs][0];
    float linv[4];
#pragma unroll
    for (int r = 0; r < 4; ++r) linv[r] = 1.0f / __shfl(lv, quad * 4 + r);
    int rowb = qt * 128 + wave * 32 + qs * 16 + quad * 4;
#pragma unroll
    for (int df = 0; df < 8; ++df) {
      int col = h * HD_ + df * 16 + l16;
#pragma unroll
      for (int r = 0; r < 4; ++r)
        O[((size_t)(b * S_ + rowb + r)) * D_ + col] = f2bf(acco[qs][df][r] * linv[r]);
    }
  }
}

extern "C" void kernel_launch(void* const* d_in, const int* in_sizes, int n_in,
                              void* d_out, int out_size, void* d_ws, size_t ws_size,
                              hipStream_t stream) {
  const float* x  = (const float*)d_in[0];
  const float* wq = (const float*)d_in[1];
  const float* wk = (const float*)d_in[2];
  const float* wv = (const float*)d_in[3];
  const float* wo = (const float*)d_in[4];

  size_t off = 0;
  char* ws = (char*)d_ws;
  u16* xb    = (u16*)(ws + off); off += (size_t)M_ * D_ * 2;          // 0..16 MiB
  u16* wqkvb = (u16*)(ws + off); off += (size_t)3 * D_ * D_ * 2;      // 16..40 MiB
  u16* wob   = (u16*)(ws + off); off += (size_t)D_ * D_ * 2;          // 40..48 MiB
  u16* Qr    = (u16*)(ws + off); off += (size_t)M_ * D_ * 2;          // 48..64 MiB
  u16* Kr    = (u16*)(ws + off); off += (size_t)M_ * D_ * 2;          // 64..80 MiB
  u16* Vp    = (u16*)(ws + off); off += (size_t)M_ * D_ * 2;          // 80..96 MiB
  float2* tab = (float2*)(ws + off); off += (size_t)S_ * 64 * sizeof(float2); // 96..97 MiB
  // Overlay: Ob (16 MiB, = M_*D_*2 exactly) on xb [0..16 MiB], dead after QKV GEMM.
  u16* Ob = xb;
  if (off > ws_size) return;

  prep_k<<<25088, 256, 0, stream>>>(x, wq, wk, wv, wo, xb, wqkvb, wob, tab);
  gemm_qkv_k<<<dim3(N3_ / 128, M_ / 128), 256, 0, stream>>>(xb, wqkvb, tab, Qr, Kr, Vp);
  flash_k<<<dim3(S_ / 128, B_ * H_), 256, 0, stream>>>(Qr, Kr, Vp, Ob);
  gemm_bt_k<float><<<dim3(D_ / 128, M_ / 128), 256, 0, stream>>>(Ob, wob, (float*)d_out, M_, D_, D_);
}